// Round 1
// baseline (1711.142 us; speedup 1.0000x reference)
//
#include <hip/hip_runtime.h>

#define NN 100000   // nodes
#define NC 200000   // cells
#define NE 300000   // edges
#define D  128
#define XP 132      // LDS pitch for 128-col rows (odd multiple of 4: conflict-free, 16B aligned)

// ---------------- attention logits + softmax denominator ----------------
__global__ __launch_bounds__(256) void k_att(const float* __restrict__ edge_attr,
                                             const float* __restrict__ emb,
                                             const int* __restrict__ ei,
                                             float* __restrict__ expv,
                                             float* __restrict__ denom) {
    int e = blockIdx.x * 4 + (threadIdx.x >> 6);
    int lane = threadIdx.x & 63;
    if (e >= NE) return;
    int send = ei[e];          // edge_index[0]
    int recv = ei[NE + e];     // edge_index[1]
    float2 a = ((const float2*)(edge_attr + (size_t)e * D))[lane];
    float2 r = ((const float2*)(emb + (size_t)recv * D))[lane];
    float2 s = ((const float2*)(emb + (size_t)send * D))[lane];
    float dr = a.x * r.x + a.y * r.y;
    float ds = a.x * s.x + a.y * s.y;
    #pragma unroll
    for (int off = 32; off > 0; off >>= 1) {
        dr += __shfl_xor(dr, off);
        ds += __shfl_xor(ds, off);
    }
    if (lane == 0) {
        const float inv_scale = 0.08838834764831845f; // 1/sqrt(128)
        float er = __expf(dr * inv_scale);
        float es = __expf(ds * inv_scale);
        expv[e] = er;
        expv[NE + e] = es;
        atomicAdd(&denom[recv], er);
        atomicAdd(&denom[send], es);
    }
}

// ---------------- weighted scatter into node_agg ----------------
__global__ __launch_bounds__(256) void k_agg(const float* __restrict__ edge_attr,
                                             const int* __restrict__ ei,
                                             const float* __restrict__ expv,
                                             const float* __restrict__ denom,
                                             float* __restrict__ na) {
    int e = blockIdx.x * 4 + (threadIdx.x >> 6);
    int lane = threadIdx.x & 63;
    if (e >= NE) return;
    int send = ei[e];
    int recv = ei[NE + e];
    float ar = expv[e] / denom[recv];
    float as = expv[NE + e] / denom[send];
    float2 a = ((const float2*)(edge_attr + (size_t)e * D))[lane];
    float* pr = na + (size_t)recv * D + lane * 2;
    float* ps = na + (size_t)send * D + lane * 2;
    atomicAdd(pr,     ar * a.x);
    atomicAdd(pr + 1, ar * a.y);
    atomicAdd(ps,     as * a.x);
    atomicAdd(ps + 1, as * a.y);
}

// ---------------- fused gather + 2-layer MLP (fp32 SGEMM) ----------------
// block: 256 threads -> 64 cells x 128 outputs; per-thread 8 cells x 4 outs.
// tx = t&31 (out group, j0=tx*4), ty = t>>5 (cell set: c = ty + 8*i).
__global__ __launch_bounds__(256) void k_mlp(const float* __restrict__ cell_attr,
                                             const float* __restrict__ na,
                                             const int* __restrict__ face,
                                             const float* __restrict__ W1,
                                             const float* __restrict__ b1,
                                             const float* __restrict__ W2,
                                             const float* __restrict__ b2,
                                             float* __restrict__ out) {
    __shared__ float xS[64 * XP];   // 33.8 KB: 64 cells x 128-k chunk (reused for h)
    __shared__ float wS[64 * 128];  // 32 KB: 64-k x 128-j weight chunk
    int t = threadIdx.x;
    int tx = t & 31;
    int ty = t >> 5;
    int c0 = blockIdx.x * 64;

    float acc[8][4];
    #pragma unroll
    for (int i = 0; i < 8; i++)
        #pragma unroll
        for (int r = 0; r < 4; r++) acc[i][r] = 0.f;

    // stage x chunk 0: k in [0,128) = cell_attr rows
    for (int idx = t; idx < 64 * 32; idx += 256) {
        int c = idx >> 5, q = idx & 31;
        float4 v = *(const float4*)(cell_attr + (size_t)(c0 + c) * D + q * 4);
        *(float4*)&xS[c * XP + q * 4] = v;
    }

    // ---- layer 1: K = 256 in 2 x-chunks x 2 w-chunks of 64 ----
    #pragma unroll 1
    for (int xc = 0; xc < 2; ++xc) {
        #pragma unroll 1
        for (int wc = 0; wc < 2; ++wc) {
            __syncthreads();
            const float* wsrc = W1 + (size_t)(xc * 128 + wc * 64) * D;
            for (int idx = t; idx < 64 * 32; idx += 256) {
                int k = idx >> 5, q = idx & 31;
                *(float4*)&wS[k * D + q * 4] = *(const float4*)(wsrc + k * D + q * 4);
            }
            __syncthreads();
            #pragma unroll 2
            for (int kk = 0; kk < 64; kk += 4) {
                float4 xv[8];
                #pragma unroll
                for (int i = 0; i < 8; i++)
                    xv[i] = *(const float4*)&xS[(ty + 8 * i) * XP + (wc * 64 + kk)];
                #pragma unroll
                for (int kq = 0; kq < 4; kq++) {
                    float4 wv = *(const float4*)&wS[(kk + kq) * D + tx * 4];
                    #pragma unroll
                    for (int i = 0; i < 8; i++) {
                        float xk = ((const float*)&xv[i])[kq];
                        acc[i][0] += xk * wv.x;
                        acc[i][1] += xk * wv.y;
                        acc[i][2] += xk * wv.z;
                        acc[i][3] += xk * wv.w;
                    }
                }
            }
        }
        if (xc == 0) {
            __syncthreads();
            // stage x chunk 1: k in [128,256) = cell_agg = mean of 3 node_agg rows
            const float inv3 = 1.f / 3.f;
            for (int idx = t; idx < 64 * 32; idx += 256) {
                int c = idx >> 5, q = idx & 31;
                int cid = c0 + c;
                int f0 = face[cid], f1 = face[NC + cid], f2 = face[2 * NC + cid];
                float4 v0 = *(const float4*)(na + (size_t)f0 * D + q * 4);
                float4 v1 = *(const float4*)(na + (size_t)f1 * D + q * 4);
                float4 v2 = *(const float4*)(na + (size_t)f2 * D + q * 4);
                float4 v;
                v.x = (v0.x + v1.x + v2.x) * inv3;
                v.y = (v0.y + v1.y + v2.y) * inv3;
                v.z = (v0.z + v1.z + v2.z) * inv3;
                v.w = (v0.w + v1.w + v2.w) * inv3;
                *(float4*)&xS[c * XP + q * 4] = v;
            }
        }
    }

    // bias + relu, park h in xS (overwrites x chunk; everyone is done reading)
    float4 b1v = *(const float4*)(b1 + tx * 4);
    __syncthreads();
    #pragma unroll
    for (int i = 0; i < 8; i++) {
        float4 h;
        h.x = fmaxf(acc[i][0] + b1v.x, 0.f);
        h.y = fmaxf(acc[i][1] + b1v.y, 0.f);
        h.z = fmaxf(acc[i][2] + b1v.z, 0.f);
        h.w = fmaxf(acc[i][3] + b1v.w, 0.f);
        *(float4*)&xS[(ty + 8 * i) * XP + tx * 4] = h;
        acc[i][0] = acc[i][1] = acc[i][2] = acc[i][3] = 0.f;
    }

    // ---- layer 2: K = 128 in 2 w-chunks of 64 ----
    #pragma unroll 1
    for (int wc = 0; wc < 2; ++wc) {
        __syncthreads();
        const float* wsrc = W2 + (size_t)(wc * 64) * D;
        for (int idx = t; idx < 64 * 32; idx += 256) {
            int k = idx >> 5, q = idx & 31;
            *(float4*)&wS[k * D + q * 4] = *(const float4*)(wsrc + k * D + q * 4);
        }
        __syncthreads();
        #pragma unroll 2
        for (int kk = 0; kk < 64; kk += 4) {
            float4 xv[8];
            #pragma unroll
            for (int i = 0; i < 8; i++)
                xv[i] = *(const float4*)&xS[(ty + 8 * i) * XP + (wc * 64 + kk)];
            #pragma unroll
            for (int kq = 0; kq < 4; kq++) {
                float4 wv = *(const float4*)&wS[(kk + kq) * D + tx * 4];
                #pragma unroll
                for (int i = 0; i < 8; i++) {
                    float xk = ((const float*)&xv[i])[kq];
                    acc[i][0] += xk * wv.x;
                    acc[i][1] += xk * wv.y;
                    acc[i][2] += xk * wv.z;
                    acc[i][3] += xk * wv.w;
                }
            }
        }
    }

    float4 b2v = *(const float4*)(b2 + tx * 4);
    #pragma unroll
    for (int i = 0; i < 8; i++) {
        float4 y;
        y.x = acc[i][0] + b2v.x;
        y.y = acc[i][1] + b2v.y;
        y.z = acc[i][2] + b2v.z;
        y.w = acc[i][3] + b2v.w;
        *(float4*)(out + (size_t)(c0 + ty + 8 * i) * D + tx * 4) = y;
    }
}

// ---------------- scatter-mean of cell features back to nodes ----------------
__global__ __launch_bounds__(256) void k_counts(const int* __restrict__ face,
                                                float* __restrict__ cnt) {
    int c = blockIdx.x * 256 + threadIdx.x;
    if (c >= NC) return;
    atomicAdd(&cnt[face[c]], 1.f);
    atomicAdd(&cnt[face[NC + c]], 1.f);
    atomicAdd(&cnt[face[2 * NC + c]], 1.f);
}

__global__ __launch_bounds__(256) void k_scatter(const float* __restrict__ cell_out,
                                                 const int* __restrict__ face,
                                                 float* __restrict__ nsum) {
    int c = blockIdx.x * 4 + (threadIdx.x >> 6);
    int lane = threadIdx.x & 63;
    if (c >= NC) return;
    float2 y = ((const float2*)(cell_out + (size_t)c * D))[lane];
    int f0 = face[c], f1 = face[NC + c], f2 = face[2 * NC + c];
    float* p0 = nsum + (size_t)f0 * D + lane * 2;
    float* p1 = nsum + (size_t)f1 * D + lane * 2;
    float* p2 = nsum + (size_t)f2 * D + lane * 2;
    atomicAdd(p0,     y.x);
    atomicAdd(p0 + 1, y.y);
    atomicAdd(p1,     y.x);
    atomicAdd(p1 + 1, y.y);
    atomicAdd(p2,     y.x);
    atomicAdd(p2 + 1, y.y);
}

__global__ __launch_bounds__(256) void k_norm(float* __restrict__ nsum,
                                              const float* __restrict__ cnt) {
    int idx = blockIdx.x * 256 + threadIdx.x;   // over N*32 float4s
    if (idx >= NN * 32) return;
    int n = idx >> 5;
    float c = cnt[n];
    c = c > 1.f ? c : 1.f;
    float inv = 1.f / c;
    float4* p = (float4*)nsum + idx;
    float4 v = *p;
    v.x *= inv; v.y *= inv; v.z *= inv; v.w *= inv;
    *p = v;
}

extern "C" void kernel_launch(void* const* d_in, const int* in_sizes, int n_in,
                              void* d_out, int out_size, void* d_ws, size_t ws_size,
                              hipStream_t stream) {
    (void)in_sizes; (void)n_in; (void)out_size; (void)ws_size;
    const float* cell_attr = (const float*)d_in[0];
    const float* edge_attr = (const float*)d_in[1];
    const float* emb       = (const float*)d_in[2];
    const int*   ei        = (const int*)d_in[3];
    const int*   face      = (const int*)d_in[4];
    const float* W1        = (const float*)d_in[5];
    const float* b1        = (const float*)d_in[6];
    const float* W2        = (const float*)d_in[7];
    const float* b2        = (const float*)d_in[8];

    float* out_cell = (float*)d_out;                    // [C*D]
    float* out_node = out_cell + (size_t)NC * D;        // [N*D] (doubles as node_agg scratch)

    float* denom = (float*)d_ws;        // [N]
    float* cnt   = denom + NN;          // [N]
    float* expv  = cnt + NN;            // [2E]

    hipMemsetAsync(denom, 0, 2 * NN * sizeof(float), stream);                  // denom + cnt
    hipMemsetAsync(out_node, 0, (size_t)NN * D * sizeof(float), stream);       // node_agg

    k_att<<<(NE + 3) / 4, 256, 0, stream>>>(edge_attr, emb, ei, expv, denom);
    k_agg<<<(NE + 3) / 4, 256, 0, stream>>>(edge_attr, ei, expv, denom, out_node);
    k_mlp<<<NC / 64, 256, 0, stream>>>(cell_attr, out_node, face, W1, b1, W2, b2, out_cell);

    hipMemsetAsync(out_node, 0, (size_t)NN * D * sizeof(float), stream);       // reuse as node sums
    k_counts<<<(NC + 255) / 256, 256, 0, stream>>>(face, cnt);
    k_scatter<<<(NC + 3) / 4, 256, 0, stream>>>(out_cell, face, out_node);
    k_norm<<<(NN * 32 + 255) / 256, 256, 0, stream>>>(out_node, cnt);
}

// Round 2
// 957.553 us; speedup vs baseline: 1.7870x; 1.7870x over previous
//
#include <hip/hip_runtime.h>

#define NN 100000   // nodes
#define NC 200000   // cells
#define NE 300000   // edges
#define D  128
#define XP 132      // LDS pitch for 128-col rows (conflict-free, 16B aligned)

// ---------------- attention logits + softmax denominator ----------------
__global__ __launch_bounds__(256) void k_att(const float* __restrict__ edge_attr,
                                             const float* __restrict__ emb,
                                             const int* __restrict__ ei,
                                             float* __restrict__ expv,
                                             float* __restrict__ denom) {
    int e = blockIdx.x * 4 + (threadIdx.x >> 6);
    int lane = threadIdx.x & 63;
    if (e >= NE) return;
    int send = ei[e];          // edge_index[0]
    int recv = ei[NE + e];     // edge_index[1]
    float2 a = ((const float2*)(edge_attr + (size_t)e * D))[lane];
    float2 r = ((const float2*)(emb + (size_t)recv * D))[lane];
    float2 s = ((const float2*)(emb + (size_t)send * D))[lane];
    float dr = a.x * r.x + a.y * r.y;
    float ds = a.x * s.x + a.y * s.y;
    #pragma unroll
    for (int off = 32; off > 0; off >>= 1) {
        dr += __shfl_xor(dr, off);
        ds += __shfl_xor(ds, off);
    }
    if (lane == 0) {
        const float inv_scale = 0.08838834764831845f; // 1/sqrt(128)
        float er = __expf(dr * inv_scale);
        float es = __expf(ds * inv_scale);
        expv[e] = er;
        expv[NE + e] = es;
        atomicAdd(&denom[recv], er);
        atomicAdd(&denom[send], es);
    }
}

// ---------------- CSR build: histogram / scan / fill ----------------
__global__ __launch_bounds__(256) void k_hist_att(const int* __restrict__ ei,
                                                  int* __restrict__ cnt) {
    int i = blockIdx.x * 256 + threadIdx.x;
    if (i >= 2 * NE) return;
    int t = (i < NE) ? ei[NE + i] : ei[i - NE];
    atomicAdd(&cnt[t], 1);
}

__global__ __launch_bounds__(256) void k_hist_face(const int* __restrict__ face,
                                                   int* __restrict__ cnt) {
    int i = blockIdx.x * 256 + threadIdx.x;
    if (i >= 3 * NC) return;
    atomicAdd(&cnt[face[i]], 1);
}

__global__ __launch_bounds__(256) void k_scan_blocks(const int* __restrict__ cnt,
                                                     int* __restrict__ bsum) {
    __shared__ int s[256];
    int t = threadIdx.x;
    int i = blockIdx.x * 256 + t;
    s[t] = (i < NN) ? cnt[i] : 0;
    __syncthreads();
    #pragma unroll
    for (int off = 128; off > 0; off >>= 1) {
        if (t < off) s[t] += s[t + off];
        __syncthreads();
    }
    if (t == 0) bsum[blockIdx.x] = s[0];
}

__global__ __launch_bounds__(512) void k_scan_top(int* __restrict__ bsum, int nb) {
    __shared__ int s[512];
    int t = threadIdx.x;
    int v = (t < nb) ? bsum[t] : 0;
    s[t] = v;
    __syncthreads();
    #pragma unroll
    for (int off = 1; off < 512; off <<= 1) {
        int x = (t >= off) ? s[t - off] : 0;
        __syncthreads();
        s[t] += x;
        __syncthreads();
    }
    if (t < nb) bsum[t] = s[t] - v;   // exclusive
}

__global__ __launch_bounds__(256) void k_scan_final(const int* __restrict__ cnt,
                                                    const int* __restrict__ bsum,
                                                    int* __restrict__ off_out,
                                                    int total) {
    __shared__ int s[256];
    int t = threadIdx.x;
    int i = blockIdx.x * 256 + t;
    int v = (i < NN) ? cnt[i] : 0;
    s[t] = v;
    __syncthreads();
    #pragma unroll
    for (int off = 1; off < 256; off <<= 1) {
        int x = (t >= off) ? s[t - off] : 0;
        __syncthreads();
        s[t] += x;
        __syncthreads();
    }
    if (i < NN) off_out[i] = s[t] - v + bsum[blockIdx.x];
    if (i == 0) off_out[NN] = total;
}

__global__ __launch_bounds__(256) void k_fill_att(const int* __restrict__ ei,
                                                  const int* __restrict__ offs,
                                                  int* __restrict__ cur,
                                                  int* __restrict__ slots) {
    int i = blockIdx.x * 256 + threadIdx.x;
    if (i >= 2 * NE) return;
    int t = (i < NE) ? ei[NE + i] : ei[i - NE];
    int pos = offs[t] + atomicAdd(&cur[t], 1);
    slots[pos] = i;
}

__global__ __launch_bounds__(256) void k_fill_face(const int* __restrict__ face,
                                                   const int* __restrict__ offs,
                                                   int* __restrict__ cur,
                                                   int* __restrict__ slots) {
    int i = blockIdx.x * 256 + threadIdx.x;
    if (i >= 3 * NC) return;
    int t = face[i];
    int pos = offs[t] + atomicAdd(&cur[t], 1);
    int c = i; if (c >= NC) c -= NC; if (c >= NC) c -= NC;   // cell id = i mod NC
    slots[pos] = c;
}

// ---------------- gather-style node aggregation (no atomics) ----------------
__global__ __launch_bounds__(256) void k_agg_gather(const float* __restrict__ edge_attr,
                                                    const float* __restrict__ expv,
                                                    const float* __restrict__ denom,
                                                    const int* __restrict__ offs,
                                                    const int* __restrict__ slots,
                                                    float* __restrict__ na) {
    int n = blockIdx.x * 4 + (threadIdx.x >> 6);
    int lane = threadIdx.x & 63;
    if (n >= NN) return;
    int s0 = offs[n], s1 = offs[n + 1];
    float2 acc = {0.f, 0.f};
    for (int s = s0; s < s1; ++s) {
        int eid = slots[s];                       // in [0, 2E)
        int row = (eid < NE) ? eid : eid - NE;
        float w = expv[eid];
        float2 a = ((const float2*)(edge_attr + (size_t)row * D))[lane];
        acc.x += w * a.x;
        acc.y += w * a.y;
    }
    float inv = (s1 > s0) ? 1.f / denom[n] : 0.f;
    float2* p = (float2*)(na + (size_t)n * D) + lane;
    float2 r; r.x = acc.x * inv; r.y = acc.y * inv;
    *p = r;
}

// ---------------- gather-style scatter-mean (no atomics) ----------------
__global__ __launch_bounds__(256) void k_smean_gather(const float* __restrict__ cell_out,
                                                      const int* __restrict__ offs,
                                                      const int* __restrict__ slots,
                                                      float* __restrict__ node_out) {
    int n = blockIdx.x * 4 + (threadIdx.x >> 6);
    int lane = threadIdx.x & 63;
    if (n >= NN) return;
    int s0 = offs[n], s1 = offs[n + 1];
    float2 acc = {0.f, 0.f};
    for (int s = s0; s < s1; ++s) {
        int c = slots[s];                         // cell id
        float2 y = ((const float2*)(cell_out + (size_t)c * D))[lane];
        acc.x += y.x;
        acc.y += y.y;
    }
    int deg = s1 - s0;
    float inv = deg ? 1.f / (float)deg : 0.f;
    float2* p = (float2*)(node_out + (size_t)n * D) + lane;
    float2 r; r.x = acc.x * inv; r.y = acc.y * inv;
    *p = r;
}

// ---------------- fused gather + 2-layer MLP (fp32 SGEMM) ----------------
__global__ __launch_bounds__(256) void k_mlp(const float* __restrict__ cell_attr,
                                             const float* __restrict__ na,
                                             const int* __restrict__ face,
                                             const float* __restrict__ W1,
                                             const float* __restrict__ b1,
                                             const float* __restrict__ W2,
                                             const float* __restrict__ b2,
                                             float* __restrict__ out) {
    __shared__ float xS[64 * XP];   // 33.8 KB
    __shared__ float wS[64 * 128];  // 32 KB
    int t = threadIdx.x;
    int tx = t & 31;
    int ty = t >> 5;
    int c0 = blockIdx.x * 64;

    float acc[8][4];
    #pragma unroll
    for (int i = 0; i < 8; i++)
        #pragma unroll
        for (int r = 0; r < 4; r++) acc[i][r] = 0.f;

    for (int idx = t; idx < 64 * 32; idx += 256) {
        int c = idx >> 5, q = idx & 31;
        float4 v = *(const float4*)(cell_attr + (size_t)(c0 + c) * D + q * 4);
        *(float4*)&xS[c * XP + q * 4] = v;
    }

    #pragma unroll 1
    for (int xc = 0; xc < 2; ++xc) {
        #pragma unroll 1
        for (int wc = 0; wc < 2; ++wc) {
            __syncthreads();
            const float* wsrc = W1 + (size_t)(xc * 128 + wc * 64) * D;
            for (int idx = t; idx < 64 * 32; idx += 256) {
                int k = idx >> 5, q = idx & 31;
                *(float4*)&wS[k * D + q * 4] = *(const float4*)(wsrc + k * D + q * 4);
            }
            __syncthreads();
            #pragma unroll 2
            for (int kk = 0; kk < 64; kk += 4) {
                float4 xv[8];
                #pragma unroll
                for (int i = 0; i < 8; i++)
                    xv[i] = *(const float4*)&xS[(ty + 8 * i) * XP + (wc * 64 + kk)];
                #pragma unroll
                for (int kq = 0; kq < 4; kq++) {
                    float4 wv = *(const float4*)&wS[(kk + kq) * D + tx * 4];
                    #pragma unroll
                    for (int i = 0; i < 8; i++) {
                        float xk = ((const float*)&xv[i])[kq];
                        acc[i][0] += xk * wv.x;
                        acc[i][1] += xk * wv.y;
                        acc[i][2] += xk * wv.z;
                        acc[i][3] += xk * wv.w;
                    }
                }
            }
        }
        if (xc == 0) {
            __syncthreads();
            const float inv3 = 1.f / 3.f;
            for (int idx = t; idx < 64 * 32; idx += 256) {
                int c = idx >> 5, q = idx & 31;
                int cid = c0 + c;
                int f0 = face[cid], f1 = face[NC + cid], f2 = face[2 * NC + cid];
                float4 v0 = *(const float4*)(na + (size_t)f0 * D + q * 4);
                float4 v1 = *(const float4*)(na + (size_t)f1 * D + q * 4);
                float4 v2 = *(const float4*)(na + (size_t)f2 * D + q * 4);
                float4 v;
                v.x = (v0.x + v1.x + v2.x) * inv3;
                v.y = (v0.y + v1.y + v2.y) * inv3;
                v.z = (v0.z + v1.z + v2.z) * inv3;
                v.w = (v0.w + v1.w + v2.w) * inv3;
                *(float4*)&xS[c * XP + q * 4] = v;
            }
        }
    }

    float4 b1v = *(const float4*)(b1 + tx * 4);
    __syncthreads();
    #pragma unroll
    for (int i = 0; i < 8; i++) {
        float4 h;
        h.x = fmaxf(acc[i][0] + b1v.x, 0.f);
        h.y = fmaxf(acc[i][1] + b1v.y, 0.f);
        h.z = fmaxf(acc[i][2] + b1v.z, 0.f);
        h.w = fmaxf(acc[i][3] + b1v.w, 0.f);
        *(float4*)&xS[(ty + 8 * i) * XP + tx * 4] = h;
        acc[i][0] = acc[i][1] = acc[i][2] = acc[i][3] = 0.f;
    }

    #pragma unroll 1
    for (int wc = 0; wc < 2; ++wc) {
        __syncthreads();
        const float* wsrc = W2 + (size_t)(wc * 64) * D;
        for (int idx = t; idx < 64 * 32; idx += 256) {
            int k = idx >> 5, q = idx & 31;
            *(float4*)&wS[k * D + q * 4] = *(const float4*)(wsrc + k * D + q * 4);
        }
        __syncthreads();
        #pragma unroll 2
        for (int kk = 0; kk < 64; kk += 4) {
            float4 xv[8];
            #pragma unroll
            for (int i = 0; i < 8; i++)
                xv[i] = *(const float4*)&xS[(ty + 8 * i) * XP + (wc * 64 + kk)];
            #pragma unroll
            for (int kq = 0; kq < 4; kq++) {
                float4 wv = *(const float4*)&wS[(kk + kq) * D + tx * 4];
                #pragma unroll
                for (int i = 0; i < 8; i++) {
                    float xk = ((const float*)&xv[i])[kq];
                    acc[i][0] += xk * wv.x;
                    acc[i][1] += xk * wv.y;
                    acc[i][2] += xk * wv.z;
                    acc[i][3] += xk * wv.w;
                }
            }
        }
    }

    float4 b2v = *(const float4*)(b2 + tx * 4);
    #pragma unroll
    for (int i = 0; i < 8; i++) {
        float4 y;
        y.x = acc[i][0] + b2v.x;
        y.y = acc[i][1] + b2v.y;
        y.z = acc[i][2] + b2v.z;
        y.w = acc[i][3] + b2v.w;
        *(float4*)(out + (size_t)(c0 + ty + 8 * i) * D + tx * 4) = y;
    }
}

extern "C" void kernel_launch(void* const* d_in, const int* in_sizes, int n_in,
                              void* d_out, int out_size, void* d_ws, size_t ws_size,
                              hipStream_t stream) {
    (void)in_sizes; (void)n_in; (void)out_size; (void)ws_size;
    const float* cell_attr = (const float*)d_in[0];
    const float* edge_attr = (const float*)d_in[1];
    const float* emb       = (const float*)d_in[2];
    const int*   ei        = (const int*)d_in[3];
    const int*   face      = (const int*)d_in[4];
    const float* W1        = (const float*)d_in[5];
    const float* b1        = (const float*)d_in[6];
    const float* W2        = (const float*)d_in[7];
    const float* b2        = (const float*)d_in[8];

    float* out_cell = (float*)d_out;                    // [C*D]
    float* out_node = out_cell + (size_t)NC * D;        // [N*D] (node_agg scratch, then final)

    // ws layout (4B units)
    float* denom  = (float*)d_ws;                 // [N]
    int*   cntA   = (int*)d_ws + NN;              // [N]
    int*   cntF   = cntA + NN;                    // [N]
    int*   curA   = cntF + NN;                    // [N]
    int*   curF   = curA + NN;                    // [N]
    float* expv   = (float*)(curF + NN);          // [2E]
    int*   offA   = (int*)(expv + 2 * NE);        // [N+1]
    int*   offF   = offA + NN + 1;                // [N+1]
    int*   slotsA = offF + NN + 1;                // [2E]
    int*   slotsF = slotsA + 2 * NE;              // [3C]
    int*   bsumA  = slotsF + 3 * NC;              // [512]
    int*   bsumF  = bsumA + 512;                  // [512]

    const int NB = (NN + 255) / 256;              // 391 scan blocks

    hipMemsetAsync(d_ws, 0, (size_t)5 * NN * 4, stream);   // denom, cntA, cntF, curA, curF

    k_att<<<(NE + 3) / 4, 256, 0, stream>>>(edge_attr, emb, ei, expv, denom);

    k_hist_att <<<(2 * NE + 255) / 256, 256, 0, stream>>>(ei, cntA);
    k_hist_face<<<(3 * NC + 255) / 256, 256, 0, stream>>>(face, cntF);

    k_scan_blocks<<<NB, 256, 0, stream>>>(cntA, bsumA);
    k_scan_top   <<<1, 512, 0, stream>>>(bsumA, NB);
    k_scan_final <<<NB, 256, 0, stream>>>(cntA, bsumA, offA, 2 * NE);

    k_scan_blocks<<<NB, 256, 0, stream>>>(cntF, bsumF);
    k_scan_top   <<<1, 512, 0, stream>>>(bsumF, NB);
    k_scan_final <<<NB, 256, 0, stream>>>(cntF, bsumF, offF, 3 * NC);

    k_fill_att <<<(2 * NE + 255) / 256, 256, 0, stream>>>(ei, offA, curA, slotsA);
    k_fill_face<<<(3 * NC + 255) / 256, 256, 0, stream>>>(face, offF, curF, slotsF);

    k_agg_gather<<<(NN + 3) / 4, 256, 0, stream>>>(edge_attr, expv, denom, offA, slotsA, out_node);

    k_mlp<<<NC / 64, 256, 0, stream>>>(cell_attr, out_node, face, W1, b1, W2, b2, out_cell);

    k_smean_gather<<<(NN + 3) / 4, 256, 0, stream>>>(out_cell, offF, slotsF, out_node);
}